// Round 6
// baseline (1908.692 us; speedup 1.0000x reference)
//
#include <hip/hip_runtime.h>

// MinkowskiConcat forward, CSR-gather (R6):
//   counts -> exclusive-scan offsets -> idxpool placement -> gather.
//   Gather v3: one wave handles EIGHT output rows (lanes 0-31 side1, 32-63 side2,
//   float4/lane). Phase-split with first+second pool-element prefetch ->
//   8 independent idxpool->feat chains in flight per half-wave.
//   Non-temporal 8KB/wave contiguous row stores.

constexpr int C_IN  = 128;
constexpr int C_OUT = 256;
constexpr int SCAN_TPB = 256;
constexpr int SCAN_EPT = 16;
constexpr int SCAN_EPB = SCAN_TPB * SCAN_EPT;     // 4096 per block
constexpr int RPW = 8;                            // rows per wave in gather

typedef float f32x4 __attribute__((ext_vector_type(4)));

__global__ void count_kernel(const int* __restrict__ m1o, const int* __restrict__ m2o,
                             int* __restrict__ counts, int n1, int n2, int n_out) {
    int i = blockIdx.x * blockDim.x + threadIdx.x;
    int n = n1 + n2;
    if (i >= n) return;
    if (i < n1) atomicAdd(&counts[m1o[i]], 1);
    else        atomicAdd(&counts[n_out + m2o[i - n1]], 1);
}

__global__ void scan_blocksums_kernel(const int* __restrict__ counts, int nc,
                                      int* __restrict__ blksums) {
    __shared__ int sdata[SCAN_TPB];
    int base = blockIdx.x * SCAN_EPB + threadIdx.x * SCAN_EPT;
    int s = 0;
    #pragma unroll
    for (int k = 0; k < SCAN_EPT; ++k) {
        int idx = base + k;
        s += (idx < nc) ? counts[idx] : 0;
    }
    sdata[threadIdx.x] = s;
    __syncthreads();
    for (int off = SCAN_TPB / 2; off > 0; off >>= 1) {
        if (threadIdx.x < off) sdata[threadIdx.x] += sdata[threadIdx.x + off];
        __syncthreads();
    }
    if (threadIdx.x == 0) blksums[blockIdx.x] = sdata[0];
}

__global__ void scan_top_kernel(int* __restrict__ blksums, int nblk,
                                int* __restrict__ offsets, int nc) {
    __shared__ int sdata[512];
    int t = threadIdx.x;
    int v = (t < nblk) ? blksums[t] : 0;
    sdata[t] = v;
    __syncthreads();
    for (int off = 1; off < 512; off <<= 1) {
        int x = (t >= off) ? sdata[t - off] : 0;
        __syncthreads();
        sdata[t] += x;
        __syncthreads();
    }
    if (t < nblk) blksums[t] = sdata[t] - v;
    if (t == 511) offsets[nc] = sdata[511];
}

__global__ void scan_write_kernel(const int* __restrict__ counts, int nc,
                                  const int* __restrict__ blksums,
                                  int* __restrict__ offsets, int* __restrict__ cursor) {
    __shared__ int sdata[SCAN_TPB];
    int t = threadIdx.x;
    int base = blockIdx.x * SCAN_EPB + t * SCAN_EPT;
    int local[SCAN_EPT];
    int s = 0;
    #pragma unroll
    for (int k = 0; k < SCAN_EPT; ++k) {
        int idx = base + k;
        int c = (idx < nc) ? counts[idx] : 0;
        local[k] = s;
        s += c;
    }
    sdata[t] = s;
    __syncthreads();
    for (int off = 1; off < SCAN_TPB; off <<= 1) {
        int x = (t >= off) ? sdata[t - off] : 0;
        __syncthreads();
        sdata[t] += x;
        __syncthreads();
    }
    int thread_excl = sdata[t] - s;
    int prefix = blksums[blockIdx.x] + thread_excl;
    #pragma unroll
    for (int k = 0; k < SCAN_EPT; ++k) {
        int idx = base + k;
        if (idx < nc) {
            int o = prefix + local[k];
            offsets[idx] = o;
            cursor[idx]  = o;
        }
    }
}

__global__ void place_kernel(const int* __restrict__ m1i, const int* __restrict__ m1o,
                             const int* __restrict__ m2i, const int* __restrict__ m2o,
                             int* __restrict__ cursor, int* __restrict__ idxpool,
                             int n1, int n2, int n_out) {
    int i = blockIdx.x * blockDim.x + threadIdx.x;
    int n = n1 + n2;
    if (i >= n) return;
    if (i < n1) {
        int pos = atomicAdd(&cursor[m1o[i]], 1);
        idxpool[pos] = m1i[i];
    } else {
        int j = i - n1;
        int pos = atomicAdd(&cursor[n_out + m2o[j]], 1);
        idxpool[pos] = m2i[j];
    }
}

// Gather v3: one wave per RPW=8 output rows; lanes 0-31 side1, 32-63 side2.
// GUARDED=false assumes n_out % RPW == 0 (exact grid, no bounds checks).
template <bool GUARDED>
__global__ void gather_kernel(const float* __restrict__ feat1,
                              const float* __restrict__ feat2,
                              const int* __restrict__ offsets,
                              const int* __restrict__ idxpool,
                              float* __restrict__ out, int n_out) {
    int wid  = (blockIdx.x * blockDim.x + threadIdx.x) >> 6;
    int lane = threadIdx.x & 63;
    int side = lane >> 5;
    int l    = lane & 31;
    long r0  = (long)wid * RPW;
    if (GUARDED && r0 >= n_out) return;

    const float* feat = side ? feat2 : feat1;
    const long obase  = side ? n_out : 0;

    // RPW+1 segment boundaries (shared between consecutive rows)
    int off[RPW + 1];
    #pragma unroll
    for (int k = 0; k <= RPW; ++k) {
        long r = r0 + k;
        if (GUARDED && r > n_out) r = n_out;
        off[k] = offsets[obase + r];
    }

    // phase 1: prefetch first TWO pool entries per row (covers 97% of segments)
    int i0[RPW], i1[RPW];
    #pragma unroll
    for (int k = 0; k < RPW; ++k) {
        int b = off[k], e = off[k + 1];
        i0[k] = (b < e)     ? idxpool[b]     : -1;
        i1[k] = (b + 1 < e) ? idxpool[b + 1] : -1;
    }

    // phase 2: first feat-row loads — 8 chains in flight
    f32x4 acc[RPW];
    #pragma unroll
    for (int k = 0; k < RPW; ++k) {
        f32x4 v = {0.f, 0.f, 0.f, 0.f};
        if (i0[k] >= 0)
            v = *reinterpret_cast<const f32x4*>(feat + (long)i0[k] * C_IN + l * 4);
        acc[k] = v;
    }

    // phase 2b: second elements (count>=2 segments, ~14%)
    #pragma unroll
    for (int k = 0; k < RPW; ++k) {
        if (i1[k] >= 0)
            acc[k] += *reinterpret_cast<const f32x4*>(feat + (long)i1[k] * C_IN + l * 4);
    }

    // phase 3: rare tails (count>=3, ~3%)
    #pragma unroll
    for (int k = 0; k < RPW; ++k) {
        for (int p = off[k] + 2; p < off[k + 1]; ++p) {
            int ir = idxpool[p];
            acc[k] += *reinterpret_cast<const f32x4*>(feat + (long)ir * C_IN + l * 4);
        }
    }

    // phase 4: non-temporal stores — wave writes 8KB contiguous
    #pragma unroll
    for (int k = 0; k < RPW; ++k) {
        long r = r0 + k;
        if (!GUARDED || r < n_out) {
            f32x4* dst = reinterpret_cast<f32x4*>(out + r * C_OUT + side * C_IN + l * 4);
            __builtin_nontemporal_store(acc[k], dst);
        }
    }
}

// ---------- fallback (R1 atomic path) if workspace is too small ----------
__global__ void zero_out_kernel(float4* __restrict__ out, long n4) {
    long i = (long)blockIdx.x * blockDim.x + threadIdx.x;
    long stride = (long)gridDim.x * blockDim.x;
    const float4 z = {0.f, 0.f, 0.f, 0.f};
    for (; i < n4; i += stride) out[i] = z;
}

__global__ void scatter_add_kernel(const float* __restrict__ feat,
                                   const int* __restrict__ map_in,
                                   const int* __restrict__ map_out,
                                   float* __restrict__ out,
                                   int n_rows, int col_off) {
    int gid = blockIdx.x * blockDim.x + threadIdx.x;
    int row = gid >> 6;
    int t   = gid & 63;
    if (row >= n_rows) return;
    int in_row  = map_in[row];
    int out_row = map_out[row];
    const float2 v = *reinterpret_cast<const float2*>(feat + (long)in_row * C_IN + t * 2);
    float* dst = out + (long)out_row * C_OUT + col_off + t * 2;
    unsafeAtomicAdd(dst,     v.x);
    unsafeAtomicAdd(dst + 1, v.y);
}

extern "C" void kernel_launch(void* const* d_in, const int* in_sizes, int n_in,
                              void* d_out, int out_size, void* d_ws, size_t ws_size,
                              hipStream_t stream) {
    const float* feat1    = (const float*)d_in[0];
    const float* feat2    = (const float*)d_in[1];
    const int*   map1_in  = (const int*)d_in[2];
    const int*   map1_out = (const int*)d_in[3];
    const int*   map2_in  = (const int*)d_in[4];
    const int*   map2_out = (const int*)d_in[5];
    float*       out      = (float*)d_out;

    const int n1    = in_sizes[0] / C_IN;      // 524288
    const int n2    = in_sizes[1] / C_IN;      // 524288
    const int n_out = out_size / C_OUT;        // 786432
    const int nc    = 2 * n_out;
    const int nblk  = (nc + SCAN_EPB - 1) / SCAN_EPB;   // 384

    size_t need = ((size_t)3 * nc + 1 + 512 + n1 + n2) * sizeof(int);
    if (ws_size >= need && nblk <= 512) {
        int* counts  = (int*)d_ws;
        int* offsets = counts + nc;             // nc+1 entries
        int* cursor  = offsets + nc + 1;
        int* blksums = cursor + nc;             // 512 entries
        int* idxpool = blksums + 512;

        (void)hipMemsetAsync(counts, 0, (size_t)nc * sizeof(int), stream);

        int n = n1 + n2;
        count_kernel<<<(n + 255) / 256, 256, 0, stream>>>(
            map1_out, map2_out, counts, n1, n2, n_out);

        scan_blocksums_kernel<<<nblk, SCAN_TPB, 0, stream>>>(counts, nc, blksums);
        scan_top_kernel<<<1, 512, 0, stream>>>(blksums, nblk, offsets, nc);
        scan_write_kernel<<<nblk, SCAN_TPB, 0, stream>>>(counts, nc, blksums, offsets, cursor);

        place_kernel<<<(n + 255) / 256, 256, 0, stream>>>(
            map1_in, map1_out, map2_in, map2_out, cursor, idxpool, n1, n2, n_out);

        long waves   = ((long)n_out + RPW - 1) / RPW;
        long threads = waves * 64;
        int  blocks  = (int)((threads + 255) / 256);
        if (n_out % RPW == 0) {
            gather_kernel<false><<<blocks, 256, 0, stream>>>(
                feat1, feat2, offsets, idxpool, out, n_out);
        } else {
            gather_kernel<true><<<blocks, 256, 0, stream>>>(
                feat1, feat2, offsets, idxpool, out, n_out);
        }
    } else {
        long n4 = (long)out_size / 4;
        zero_out_kernel<<<2048, 256, 0, stream>>>((float4*)out, n4);
        scatter_add_kernel<<<(n1 + 3) / 4, 256, 0, stream>>>(
            feat1, map1_in, map1_out, out, n1, 0);
        scatter_add_kernel<<<(n2 + 3) / 4, 256, 0, stream>>>(
            feat2, map2_in, map2_out, out, n2, C_IN);
    }
}

// Round 7
// 544.612 us; speedup vs baseline: 3.5047x; 3.5047x over previous
//
#include <hip/hip_runtime.h>

// MinkowskiConcat forward, CSR-gather (R7 = R6 + __launch_bounds__):
//   R6 lesson: without __launch_bounds__, hipcc assumes 1024-thread blocks and
//   caps VGPRs at 64 -> RPW=8 state spilled to scratch -> WRITE_SIZE 6 GB (7.5x).
//   __launch_bounds__(256) lifts the cap; RPW=8 register state fits.

constexpr int C_IN  = 128;
constexpr int C_OUT = 256;
constexpr int SCAN_TPB = 256;
constexpr int SCAN_EPT = 16;
constexpr int SCAN_EPB = SCAN_TPB * SCAN_EPT;     // 4096 per block
constexpr int RPW = 8;                            // rows per wave in gather

typedef float f32x4 __attribute__((ext_vector_type(4)));

__global__ void count_kernel(const int* __restrict__ m1o, const int* __restrict__ m2o,
                             int* __restrict__ counts, int n1, int n2, int n_out) {
    int i = blockIdx.x * blockDim.x + threadIdx.x;
    int n = n1 + n2;
    if (i >= n) return;
    if (i < n1) atomicAdd(&counts[m1o[i]], 1);
    else        atomicAdd(&counts[n_out + m2o[i - n1]], 1);
}

__global__ void scan_blocksums_kernel(const int* __restrict__ counts, int nc,
                                      int* __restrict__ blksums) {
    __shared__ int sdata[SCAN_TPB];
    int base = blockIdx.x * SCAN_EPB + threadIdx.x * SCAN_EPT;
    int s = 0;
    #pragma unroll
    for (int k = 0; k < SCAN_EPT; ++k) {
        int idx = base + k;
        s += (idx < nc) ? counts[idx] : 0;
    }
    sdata[threadIdx.x] = s;
    __syncthreads();
    for (int off = SCAN_TPB / 2; off > 0; off >>= 1) {
        if (threadIdx.x < off) sdata[threadIdx.x] += sdata[threadIdx.x + off];
        __syncthreads();
    }
    if (threadIdx.x == 0) blksums[blockIdx.x] = sdata[0];
}

__global__ void scan_top_kernel(int* __restrict__ blksums, int nblk,
                                int* __restrict__ offsets, int nc) {
    __shared__ int sdata[512];
    int t = threadIdx.x;
    int v = (t < nblk) ? blksums[t] : 0;
    sdata[t] = v;
    __syncthreads();
    for (int off = 1; off < 512; off <<= 1) {
        int x = (t >= off) ? sdata[t - off] : 0;
        __syncthreads();
        sdata[t] += x;
        __syncthreads();
    }
    if (t < nblk) blksums[t] = sdata[t] - v;
    if (t == 511) offsets[nc] = sdata[511];
}

__global__ void scan_write_kernel(const int* __restrict__ counts, int nc,
                                  const int* __restrict__ blksums,
                                  int* __restrict__ offsets, int* __restrict__ cursor) {
    __shared__ int sdata[SCAN_TPB];
    int t = threadIdx.x;
    int base = blockIdx.x * SCAN_EPB + t * SCAN_EPT;
    int local[SCAN_EPT];
    int s = 0;
    #pragma unroll
    for (int k = 0; k < SCAN_EPT; ++k) {
        int idx = base + k;
        int c = (idx < nc) ? counts[idx] : 0;
        local[k] = s;
        s += c;
    }
    sdata[t] = s;
    __syncthreads();
    for (int off = 1; off < SCAN_TPB; off <<= 1) {
        int x = (t >= off) ? sdata[t - off] : 0;
        __syncthreads();
        sdata[t] += x;
        __syncthreads();
    }
    int thread_excl = sdata[t] - s;
    int prefix = blksums[blockIdx.x] + thread_excl;
    #pragma unroll
    for (int k = 0; k < SCAN_EPT; ++k) {
        int idx = base + k;
        if (idx < nc) {
            int o = prefix + local[k];
            offsets[idx] = o;
            cursor[idx]  = o;
        }
    }
}

__global__ void place_kernel(const int* __restrict__ m1i, const int* __restrict__ m1o,
                             const int* __restrict__ m2i, const int* __restrict__ m2o,
                             int* __restrict__ cursor, int* __restrict__ idxpool,
                             int n1, int n2, int n_out) {
    int i = blockIdx.x * blockDim.x + threadIdx.x;
    int n = n1 + n2;
    if (i >= n) return;
    if (i < n1) {
        int pos = atomicAdd(&cursor[m1o[i]], 1);
        idxpool[pos] = m1i[i];
    } else {
        int j = i - n1;
        int pos = atomicAdd(&cursor[n_out + m2o[j]], 1);
        idxpool[pos] = m2i[j];
    }
}

// Gather v3: one wave per RPW=8 output rows; lanes 0-31 side1, 32-63 side2.
// __launch_bounds__(256): VGPR cap 256 (not 64) -> no scratch spill.
template <bool GUARDED>
__global__ __launch_bounds__(256)
void gather_kernel(const float* __restrict__ feat1,
                   const float* __restrict__ feat2,
                   const int* __restrict__ offsets,
                   const int* __restrict__ idxpool,
                   float* __restrict__ out, int n_out) {
    int wid  = (blockIdx.x * blockDim.x + threadIdx.x) >> 6;
    int lane = threadIdx.x & 63;
    int side = lane >> 5;
    int l    = lane & 31;
    long r0  = (long)wid * RPW;
    if (GUARDED && r0 >= n_out) return;

    const float* feat = side ? feat2 : feat1;
    const long obase  = side ? n_out : 0;

    // RPW+1 segment boundaries (shared between consecutive rows)
    int off[RPW + 1];
    #pragma unroll
    for (int k = 0; k <= RPW; ++k) {
        long r = r0 + k;
        if (GUARDED && r > n_out) r = n_out;
        off[k] = offsets[obase + r];
    }

    // phase 1: prefetch first TWO pool entries per row (covers 97% of segments)
    int i0[RPW], i1[RPW];
    #pragma unroll
    for (int k = 0; k < RPW; ++k) {
        int b = off[k], e = off[k + 1];
        i0[k] = (b < e)     ? idxpool[b]     : -1;
        i1[k] = (b + 1 < e) ? idxpool[b + 1] : -1;
    }

    // phase 2: first feat-row loads — 8 chains in flight per half-wave
    f32x4 acc[RPW];
    #pragma unroll
    for (int k = 0; k < RPW; ++k) {
        f32x4 v = {0.f, 0.f, 0.f, 0.f};
        if (i0[k] >= 0)
            v = *reinterpret_cast<const f32x4*>(feat + (long)i0[k] * C_IN + l * 4);
        acc[k] = v;
    }

    // phase 2b: second elements (count>=2 segments, ~14%)
    #pragma unroll
    for (int k = 0; k < RPW; ++k) {
        if (i1[k] >= 0)
            acc[k] += *reinterpret_cast<const f32x4*>(feat + (long)i1[k] * C_IN + l * 4);
    }

    // phase 3: rare tails (count>=3, ~3%)
    #pragma unroll
    for (int k = 0; k < RPW; ++k) {
        for (int p = off[k] + 2; p < off[k + 1]; ++p) {
            int ir = idxpool[p];
            acc[k] += *reinterpret_cast<const f32x4*>(feat + (long)ir * C_IN + l * 4);
        }
    }

    // phase 4: non-temporal stores — wave writes 8KB contiguous
    #pragma unroll
    for (int k = 0; k < RPW; ++k) {
        long r = r0 + k;
        if (!GUARDED || r < n_out) {
            f32x4* dst = reinterpret_cast<f32x4*>(out + r * C_OUT + side * C_IN + l * 4);
            __builtin_nontemporal_store(acc[k], dst);
        }
    }
}

// ---------- fallback (R1 atomic path) if workspace is too small ----------
__global__ void zero_out_kernel(float4* __restrict__ out, long n4) {
    long i = (long)blockIdx.x * blockDim.x + threadIdx.x;
    long stride = (long)gridDim.x * blockDim.x;
    const float4 z = {0.f, 0.f, 0.f, 0.f};
    for (; i < n4; i += stride) out[i] = z;
}

__global__ void scatter_add_kernel(const float* __restrict__ feat,
                                   const int* __restrict__ map_in,
                                   const int* __restrict__ map_out,
                                   float* __restrict__ out,
                                   int n_rows, int col_off) {
    int gid = blockIdx.x * blockDim.x + threadIdx.x;
    int row = gid >> 6;
    int t   = gid & 63;
    if (row >= n_rows) return;
    int in_row  = map_in[row];
    int out_row = map_out[row];
    const float2 v = *reinterpret_cast<const float2*>(feat + (long)in_row * C_IN + t * 2);
    float* dst = out + (long)out_row * C_OUT + col_off + t * 2;
    unsafeAtomicAdd(dst,     v.x);
    unsafeAtomicAdd(dst + 1, v.y);
}

extern "C" void kernel_launch(void* const* d_in, const int* in_sizes, int n_in,
                              void* d_out, int out_size, void* d_ws, size_t ws_size,
                              hipStream_t stream) {
    const float* feat1    = (const float*)d_in[0];
    const float* feat2    = (const float*)d_in[1];
    const int*   map1_in  = (const int*)d_in[2];
    const int*   map1_out = (const int*)d_in[3];
    const int*   map2_in  = (const int*)d_in[4];
    const int*   map2_out = (const int*)d_in[5];
    float*       out      = (float*)d_out;

    const int n1    = in_sizes[0] / C_IN;      // 524288
    const int n2    = in_sizes[1] / C_IN;      // 524288
    const int n_out = out_size / C_OUT;        // 786432
    const int nc    = 2 * n_out;
    const int nblk  = (nc + SCAN_EPB - 1) / SCAN_EPB;   // 384

    size_t need = ((size_t)3 * nc + 1 + 512 + n1 + n2) * sizeof(int);
    if (ws_size >= need && nblk <= 512) {
        int* counts  = (int*)d_ws;
        int* offsets = counts + nc;             // nc+1 entries
        int* cursor  = offsets + nc + 1;
        int* blksums = cursor + nc;             // 512 entries
        int* idxpool = blksums + 512;

        (void)hipMemsetAsync(counts, 0, (size_t)nc * sizeof(int), stream);

        int n = n1 + n2;
        count_kernel<<<(n + 255) / 256, 256, 0, stream>>>(
            map1_out, map2_out, counts, n1, n2, n_out);

        scan_blocksums_kernel<<<nblk, SCAN_TPB, 0, stream>>>(counts, nc, blksums);
        scan_top_kernel<<<1, 512, 0, stream>>>(blksums, nblk, offsets, nc);
        scan_write_kernel<<<nblk, SCAN_TPB, 0, stream>>>(counts, nc, blksums, offsets, cursor);

        place_kernel<<<(n + 255) / 256, 256, 0, stream>>>(
            map1_in, map1_out, map2_in, map2_out, cursor, idxpool, n1, n2, n_out);

        long waves   = ((long)n_out + RPW - 1) / RPW;
        long threads = waves * 64;
        int  blocks  = (int)((threads + 255) / 256);
        if (n_out % RPW == 0) {
            gather_kernel<false><<<blocks, 256, 0, stream>>>(
                feat1, feat2, offsets, idxpool, out, n_out);
        } else {
            gather_kernel<true><<<blocks, 256, 0, stream>>>(
                feat1, feat2, offsets, idxpool, out, n_out);
        }
    } else {
        long n4 = (long)out_size / 4;
        zero_out_kernel<<<2048, 256, 0, stream>>>((float4*)out, n4);
        scatter_add_kernel<<<(n1 + 3) / 4, 256, 0, stream>>>(
            feat1, map1_in, map1_out, out, n1, 0);
        scatter_add_kernel<<<(n2 + 3) / 4, 256, 0, stream>>>(
            feat2, map2_in, map2_out, out, n2, C_IN);
    }
}

// Round 8
// 406.110 us; speedup vs baseline: 4.6999x; 1.3410x over previous
//
#include <hip/hip_runtime.h>

// MinkowskiConcat forward, slot-direct formulation (R8):
//   place: pos = atomicAdd(cnt[key]); pos<4 -> slots[4*key+pos]=in_row; else overflow list.
//   gather: per output row, load cnt + int4 slots (direct addresses, parallel) -> <=4 feat
//   rows -> non-temporal full-row store. No scan, no idxpool indirection level.
//   fixup: rare overflow entries (Poisson lambda=0.667 -> ~1e3 total) via f32 atomics.
//   Fallbacks: CSR path (R5, 23.1MB) then atomic path.

constexpr int C_IN  = 128;
constexpr int C_OUT = 256;
constexpr int RPW   = 4;            // rows per wave (per half-wave side) in gather
constexpr int NSLOT = 4;
constexpr int OVF_CAP = 262144;     // 230x margin over expected ~1.1K overflow entries
constexpr int SCAN_TPB = 256;
constexpr int SCAN_EPT = 16;
constexpr int SCAN_EPB = SCAN_TPB * SCAN_EPT;

typedef float f32x4 __attribute__((ext_vector_type(4)));

// ---------------- slot-direct path ----------------

__global__ __launch_bounds__(256)
void place_slots_kernel(const int* __restrict__ m1i, const int* __restrict__ m1o,
                        const int* __restrict__ m2i, const int* __restrict__ m2o,
                        int* __restrict__ cnt, int* __restrict__ slots,
                        int2* __restrict__ ovf, int* __restrict__ ovf_n,
                        int n1, int n2, int n_out) {
    int i = blockIdx.x * blockDim.x + threadIdx.x;
    int n = n1 + n2;
    if (i >= n) return;
    int key, in_row;
    if (i < n1) { key = m1o[i];          in_row = m1i[i]; }
    else        { key = n_out + m2o[i - n1]; in_row = m2i[i - n1]; }
    int pos = atomicAdd(&cnt[key], 1);
    if (pos < NSLOT) {
        slots[(long)key * NSLOT + pos] = in_row;
    } else {
        int p = atomicAdd(ovf_n, 1);
        if (p < OVF_CAP) ovf[p] = make_int2(key, in_row);
    }
}

template <bool GUARDED>
__global__ __launch_bounds__(256)
void gather_slots_kernel(const float* __restrict__ feat1,
                         const float* __restrict__ feat2,
                         const int* __restrict__ cnt,
                         const int* __restrict__ slots,
                         float* __restrict__ out, int n_out) {
    int wid  = (blockIdx.x * blockDim.x + threadIdx.x) >> 6;
    int lane = threadIdx.x & 63;
    int side = lane >> 5;
    int l    = lane & 31;
    long r0  = (long)wid * RPW;
    if (GUARDED && r0 >= n_out) return;

    const float* feat = side ? feat2 : feat1;
    const long kbase  = (side ? (long)n_out : 0) + r0;

    // all cnt + slot loads are direct-addressed -> issued in parallel at t=0
    int  c[RPW];
    int4 s[RPW];
    #pragma unroll
    for (int k = 0; k < RPW; ++k) {
        long key = kbase + k;
        bool ok  = !GUARDED || (r0 + k) < n_out;
        c[k] = ok ? cnt[key] : 0;
        s[k] = ok ? *reinterpret_cast<const int4*>(slots + key * NSLOT)
                  : make_int4(0, 0, 0, 0);
    }

    f32x4 acc[RPW];
    #pragma unroll
    for (int k = 0; k < RPW; ++k) {
        f32x4 v = {0.f, 0.f, 0.f, 0.f};
        if (c[k] > 0)
            v = *reinterpret_cast<const f32x4*>(feat + (long)s[k].x * C_IN + l * 4);
        acc[k] = v;
    }
    #pragma unroll
    for (int k = 0; k < RPW; ++k)
        if (c[k] > 1)
            acc[k] += *reinterpret_cast<const f32x4*>(feat + (long)s[k].y * C_IN + l * 4);
    #pragma unroll
    for (int k = 0; k < RPW; ++k)
        if (c[k] > 2)
            acc[k] += *reinterpret_cast<const f32x4*>(feat + (long)s[k].z * C_IN + l * 4);
    #pragma unroll
    for (int k = 0; k < RPW; ++k)
        if (c[k] > 3)
            acc[k] += *reinterpret_cast<const f32x4*>(feat + (long)s[k].w * C_IN + l * 4);

    #pragma unroll
    for (int k = 0; k < RPW; ++k) {
        long r = r0 + k;
        if (!GUARDED || r < n_out) {
            f32x4* dst = reinterpret_cast<f32x4*>(out + r * C_OUT + side * C_IN + l * 4);
            __builtin_nontemporal_store(acc[k], dst);
        }
    }
}

// one wave per overflow entry (grid-stride), 128ch via 2 floats/lane, f32 atomics
__global__ __launch_bounds__(256)
void fixup_kernel(const float* __restrict__ feat1, const float* __restrict__ feat2,
                  const int2* __restrict__ ovf, const int* __restrict__ ovf_n,
                  float* __restrict__ out, int n_out) {
    int wid  = (blockIdx.x * blockDim.x + threadIdx.x) >> 6;
    int lane = threadIdx.x & 63;
    int total = *ovf_n;
    if (total > OVF_CAP) total = OVF_CAP;
    int nw = (gridDim.x * blockDim.x) >> 6;
    for (int e = wid; e < total; e += nw) {
        int2 kr  = ovf[e];
        int side = (kr.x >= n_out) ? 1 : 0;
        long r   = kr.x - (side ? n_out : 0);
        const float* feat = side ? feat2 : feat1;
        const float2 v = *reinterpret_cast<const float2*>(feat + (long)kr.y * C_IN + lane * 2);
        float* dst = out + r * C_OUT + side * C_IN + lane * 2;
        unsafeAtomicAdd(dst,     v.x);
        unsafeAtomicAdd(dst + 1, v.y);
    }
}

// ---------------- CSR fallback path (R5-proven, RPW=4 + launch_bounds) ----------------

__global__ void count_kernel(const int* __restrict__ m1o, const int* __restrict__ m2o,
                             int* __restrict__ counts, int n1, int n2, int n_out) {
    int i = blockIdx.x * blockDim.x + threadIdx.x;
    int n = n1 + n2;
    if (i >= n) return;
    if (i < n1) atomicAdd(&counts[m1o[i]], 1);
    else        atomicAdd(&counts[n_out + m2o[i - n1]], 1);
}

__global__ void scan_blocksums_kernel(const int* __restrict__ counts, int nc,
                                      int* __restrict__ blksums) {
    __shared__ int sdata[SCAN_TPB];
    int base = blockIdx.x * SCAN_EPB + threadIdx.x * SCAN_EPT;
    int s = 0;
    #pragma unroll
    for (int k = 0; k < SCAN_EPT; ++k) {
        int idx = base + k;
        s += (idx < nc) ? counts[idx] : 0;
    }
    sdata[threadIdx.x] = s;
    __syncthreads();
    for (int off = SCAN_TPB / 2; off > 0; off >>= 1) {
        if (threadIdx.x < off) sdata[threadIdx.x] += sdata[threadIdx.x + off];
        __syncthreads();
    }
    if (threadIdx.x == 0) blksums[blockIdx.x] = sdata[0];
}

__global__ void scan_top_kernel(int* __restrict__ blksums, int nblk,
                                int* __restrict__ offsets, int nc) {
    __shared__ int sdata[512];
    int t = threadIdx.x;
    int v = (t < nblk) ? blksums[t] : 0;
    sdata[t] = v;
    __syncthreads();
    for (int off = 1; off < 512; off <<= 1) {
        int x = (t >= off) ? sdata[t - off] : 0;
        __syncthreads();
        sdata[t] += x;
        __syncthreads();
    }
    if (t < nblk) blksums[t] = sdata[t] - v;
    if (t == 511) offsets[nc] = sdata[511];
}

__global__ void scan_write_kernel(const int* __restrict__ counts, int nc,
                                  const int* __restrict__ blksums,
                                  int* __restrict__ offsets, int* __restrict__ cursor) {
    __shared__ int sdata[SCAN_TPB];
    int t = threadIdx.x;
    int base = blockIdx.x * SCAN_EPB + t * SCAN_EPT;
    int local[SCAN_EPT];
    int s = 0;
    #pragma unroll
    for (int k = 0; k < SCAN_EPT; ++k) {
        int idx = base + k;
        int c = (idx < nc) ? counts[idx] : 0;
        local[k] = s;
        s += c;
    }
    sdata[t] = s;
    __syncthreads();
    for (int off = 1; off < SCAN_TPB; off <<= 1) {
        int x = (t >= off) ? sdata[t - off] : 0;
        __syncthreads();
        sdata[t] += x;
        __syncthreads();
    }
    int thread_excl = sdata[t] - s;
    int prefix = blksums[blockIdx.x] + thread_excl;
    #pragma unroll
    for (int k = 0; k < SCAN_EPT; ++k) {
        int idx = base + k;
        if (idx < nc) {
            int o = prefix + local[k];
            offsets[idx] = o;
            cursor[idx]  = o;
        }
    }
}

__global__ void place_kernel(const int* __restrict__ m1i, const int* __restrict__ m1o,
                             const int* __restrict__ m2i, const int* __restrict__ m2o,
                             int* __restrict__ cursor, int* __restrict__ idxpool,
                             int n1, int n2, int n_out) {
    int i = blockIdx.x * blockDim.x + threadIdx.x;
    int n = n1 + n2;
    if (i >= n) return;
    if (i < n1) {
        int pos = atomicAdd(&cursor[m1o[i]], 1);
        idxpool[pos] = m1i[i];
    } else {
        int j = i - n1;
        int pos = atomicAdd(&cursor[n_out + m2o[j]], 1);
        idxpool[pos] = m2i[j];
    }
}

template <bool GUARDED>
__global__ __launch_bounds__(256)
void gather_csr_kernel(const float* __restrict__ feat1,
                       const float* __restrict__ feat2,
                       const int* __restrict__ offsets,
                       const int* __restrict__ idxpool,
                       float* __restrict__ out, int n_out) {
    int wid  = (blockIdx.x * blockDim.x + threadIdx.x) >> 6;
    int lane = threadIdx.x & 63;
    int side = lane >> 5;
    int l    = lane & 31;
    long r0  = (long)wid * RPW;
    if (GUARDED && r0 >= n_out) return;

    const float* feat = side ? feat2 : feat1;
    const long obase  = side ? n_out : 0;

    int off[RPW + 1];
    #pragma unroll
    for (int k = 0; k <= RPW; ++k) {
        long r = r0 + k;
        if (GUARDED && r > n_out) r = n_out;
        off[k] = offsets[obase + r];
    }

    int i0[RPW], i1[RPW];
    #pragma unroll
    for (int k = 0; k < RPW; ++k) {
        int b = off[k], e = off[k + 1];
        i0[k] = (b < e)     ? idxpool[b]     : -1;
        i1[k] = (b + 1 < e) ? idxpool[b + 1] : -1;
    }

    f32x4 acc[RPW];
    #pragma unroll
    for (int k = 0; k < RPW; ++k) {
        f32x4 v = {0.f, 0.f, 0.f, 0.f};
        if (i0[k] >= 0)
            v = *reinterpret_cast<const f32x4*>(feat + (long)i0[k] * C_IN + l * 4);
        acc[k] = v;
    }
    #pragma unroll
    for (int k = 0; k < RPW; ++k) {
        if (i1[k] >= 0)
            acc[k] += *reinterpret_cast<const f32x4*>(feat + (long)i1[k] * C_IN + l * 4);
    }
    #pragma unroll
    for (int k = 0; k < RPW; ++k) {
        for (int p = off[k] + 2; p < off[k + 1]; ++p) {
            int ir = idxpool[p];
            acc[k] += *reinterpret_cast<const f32x4*>(feat + (long)ir * C_IN + l * 4);
        }
    }
    #pragma unroll
    for (int k = 0; k < RPW; ++k) {
        long r = r0 + k;
        if (!GUARDED || r < n_out) {
            f32x4* dst = reinterpret_cast<f32x4*>(out + r * C_OUT + side * C_IN + l * 4);
            __builtin_nontemporal_store(acc[k], dst);
        }
    }
}

// ---------------- atomic last-resort path ----------------

__global__ void zero_out_kernel(float4* __restrict__ out, long n4) {
    long i = (long)blockIdx.x * blockDim.x + threadIdx.x;
    long stride = (long)gridDim.x * blockDim.x;
    const float4 z = {0.f, 0.f, 0.f, 0.f};
    for (; i < n4; i += stride) out[i] = z;
}

__global__ void scatter_add_kernel(const float* __restrict__ feat,
                                   const int* __restrict__ map_in,
                                   const int* __restrict__ map_out,
                                   float* __restrict__ out,
                                   int n_rows, int col_off) {
    int gid = blockIdx.x * blockDim.x + threadIdx.x;
    int row = gid >> 6;
    int t   = gid & 63;
    if (row >= n_rows) return;
    int in_row  = map_in[row];
    int out_row = map_out[row];
    const float2 v = *reinterpret_cast<const float2*>(feat + (long)in_row * C_IN + t * 2);
    float* dst = out + (long)out_row * C_OUT + col_off + t * 2;
    unsafeAtomicAdd(dst,     v.x);
    unsafeAtomicAdd(dst + 1, v.y);
}

extern "C" void kernel_launch(void* const* d_in, const int* in_sizes, int n_in,
                              void* d_out, int out_size, void* d_ws, size_t ws_size,
                              hipStream_t stream) {
    const float* feat1    = (const float*)d_in[0];
    const float* feat2    = (const float*)d_in[1];
    const int*   map1_in  = (const int*)d_in[2];
    const int*   map1_out = (const int*)d_in[3];
    const int*   map2_in  = (const int*)d_in[4];
    const int*   map2_out = (const int*)d_in[5];
    float*       out      = (float*)d_out;

    const int n1    = in_sizes[0] / C_IN;      // 524288
    const int n2    = in_sizes[1] / C_IN;      // 524288
    const int n_out = out_size / C_OUT;        // 786432
    const int nc    = 2 * n_out;
    const int n     = n1 + n2;

    // slot-direct path: cnt[nc] + slots[NSLOT*nc] + ovf[2*OVF_CAP] + ovf_n + pad
    size_t need_slots = ((size_t)nc * (1 + NSLOT) + 2 * (size_t)OVF_CAP + 16) * sizeof(int);
    size_t need_csr   = ((size_t)3 * nc + 1 + 512 + n1 + n2) * sizeof(int);
    const int nblk    = (nc + SCAN_EPB - 1) / SCAN_EPB;

    if (ws_size >= need_slots) {
        int*  cnt   = (int*)d_ws;
        int*  slots = cnt + nc;                       // NSLOT*nc ints, 16B-aligned
        int2* ovf   = (int2*)(slots + (size_t)NSLOT * nc);
        int*  ovf_n = (int*)(ovf + OVF_CAP);

        (void)hipMemsetAsync(cnt, 0, (size_t)nc * sizeof(int), stream);
        (void)hipMemsetAsync(ovf_n, 0, sizeof(int), stream);

        place_slots_kernel<<<(n + 255) / 256, 256, 0, stream>>>(
            map1_in, map1_out, map2_in, map2_out, cnt, slots, ovf, ovf_n, n1, n2, n_out);

        long waves   = ((long)n_out + RPW - 1) / RPW;
        long threads = waves * 64;
        int  blocks  = (int)((threads + 255) / 256);
        if (n_out % RPW == 0)
            gather_slots_kernel<false><<<blocks, 256, 0, stream>>>(
                feat1, feat2, cnt, slots, out, n_out);
        else
            gather_slots_kernel<true><<<blocks, 256, 0, stream>>>(
                feat1, feat2, cnt, slots, out, n_out);

        fixup_kernel<<<2048, 256, 0, stream>>>(feat1, feat2, ovf, ovf_n, out, n_out);
    } else if (ws_size >= need_csr && nblk <= 512) {
        int* counts  = (int*)d_ws;
        int* offsets = counts + nc;
        int* cursor  = offsets + nc + 1;
        int* blksums = cursor + nc;
        int* idxpool = blksums + 512;

        (void)hipMemsetAsync(counts, 0, (size_t)nc * sizeof(int), stream);
        count_kernel<<<(n + 255) / 256, 256, 0, stream>>>(
            map1_out, map2_out, counts, n1, n2, n_out);
        scan_blocksums_kernel<<<nblk, SCAN_TPB, 0, stream>>>(counts, nc, blksums);
        scan_top_kernel<<<1, 512, 0, stream>>>(blksums, nblk, offsets, nc);
        scan_write_kernel<<<nblk, SCAN_TPB, 0, stream>>>(counts, nc, blksums, offsets, cursor);
        place_kernel<<<(n + 255) / 256, 256, 0, stream>>>(
            map1_in, map1_out, map2_in, map2_out, cursor, idxpool, n1, n2, n_out);

        long waves   = ((long)n_out + RPW - 1) / RPW;
        long threads = waves * 64;
        int  blocks  = (int)((threads + 255) / 256);
        if (n_out % RPW == 0)
            gather_csr_kernel<false><<<blocks, 256, 0, stream>>>(
                feat1, feat2, offsets, idxpool, out, n_out);
        else
            gather_csr_kernel<true><<<blocks, 256, 0, stream>>>(
                feat1, feat2, offsets, idxpool, out, n_out);
    } else {
        long n4 = (long)out_size / 4;
        zero_out_kernel<<<2048, 256, 0, stream>>>((float4*)out, n4);
        scatter_add_kernel<<<(n1 + 3) / 4, 256, 0, stream>>>(
            feat1, map1_in, map1_out, out, n1, 0);
        scatter_add_kernel<<<(n2 + 3) / 4, 256, 0, stream>>>(
            feat2, map2_in, map2_out, out, n2, C_IN);
    }
}